// Round 5
// baseline (282.934 us; speedup 1.0000x reference)
//
#include <hip/hip_runtime.h>

#define N_PTS 32768
#define BATCH 16
#define PIO2F 1.5707963705062866f

// ---------------- repetition macros ----------------
#define REP16(M) M(0)M(1)M(2)M(3)M(4)M(5)M(6)M(7)M(8)M(9)M(10)M(11)M(12)M(13)M(14)M(15)
#define REP16I(M) M(0)M(1)M(2)M(3)M(4)M(5)M(6)M(7)M(8)M(9)M(10)M(11)M(12)M(13)M(14)M(15)
#define REP62(M) M(0)M(1)M(2)M(3)M(4)M(5)M(6)M(7)M(8)M(9)M(10)M(11)M(12)M(13)M(14)M(15)\
M(16)M(17)M(18)M(19)M(20)M(21)M(22)M(23)M(24)M(25)M(26)M(27)M(28)M(29)M(30)M(31)\
M(32)M(33)M(34)M(35)M(36)M(37)M(38)M(39)M(40)M(41)M(42)M(43)M(44)M(45)M(46)M(47)\
M(48)M(49)M(50)M(51)M(52)M(53)M(54)M(55)M(56)M(57)M(58)M(59)M(60)M(61)
#define REP52(M) M(0)M(1)M(2)M(3)M(4)M(5)M(6)M(7)M(8)M(9)M(10)M(11)M(12)M(13)M(14)M(15)\
M(16)M(17)M(18)M(19)M(20)M(21)M(22)M(23)M(24)M(25)M(26)M(27)M(28)M(29)M(30)M(31)\
M(32)M(33)M(34)M(35)M(36)M(37)M(38)M(39)M(40)M(41)M(42)M(43)M(44)M(45)M(46)M(47)\
M(48)M(49)M(50)M(51)

// posenc into named scalars h_0..h_61 (needs x0, x1 in scope)
#define PE(sc, ia, ib, ic, id) { float a0 = x0 * sc, a1 = x1 * sc; \
    h_##ia = sinf(a0); h_##ib = sinf(a1); \
    h_##ic = sinf(a0 + PIO2F); h_##id = sinf(a1 + PIO2F); }
#define POSENC_BODY \
    h_0 = x0; h_1 = x1; \
    PE(1.f,2,3,32,33)      PE(2.f,4,5,34,35)      PE(4.f,6,7,36,37) \
    PE(8.f,8,9,38,39)      PE(16.f,10,11,40,41)   PE(32.f,12,13,42,43) \
    PE(64.f,14,15,44,45)   PE(128.f,16,17,46,47)  PE(256.f,18,19,48,49) \
    PE(512.f,20,21,50,51)  PE(1024.f,22,23,52,53) PE(2048.f,24,25,54,55) \
    PE(4096.f,26,27,56,57) PE(8192.f,28,29,58,59) PE(16384.f,30,31,60,61)

// ---------------- helpers ----------------
__device__ __forceinline__ float silu_f(float v) {
    return v * __builtin_amdgcn_rcpf(1.0f + __expf(-v));
}

__device__ __forceinline__ float wave_sum(float v) {
    #pragma unroll
    for (int off = 1; off < 64; off <<= 1) v += __shfl_xor(v, off, 64);
    return v;
}

// ---------------- kernel 1: posenc, feature-major output H0T[i][p] ----------------
__global__ void posenc_kernel(const float* __restrict__ x, float* __restrict__ H0T) {
    int p = blockIdx.x * 256 + threadIdx.x;
    float x0 = x[2 * p], x1 = x[2 * p + 1];
#define DH(i) float h_##i;
    REP62(DH)
#undef DH
    POSENC_BODY
#define SH(i) H0T[(size_t)(i) * N_PTS + p] = h_##i;
    REP62(SH)
#undef SH
}

// ---------------- kernel 2: hyper-weights wv (4 layers fused) ----------------
__global__ void wv_kernel(
    const float* __restrict__ latent,
    const float* __restrict__ pw0, const float* __restrict__ pb0,
    const float* __restrict__ lnw0, const float* __restrict__ lnb0,
    const float* __restrict__ pw1, const float* __restrict__ pb1,
    const float* __restrict__ lnw1, const float* __restrict__ lnb1,
    const float* __restrict__ pw2, const float* __restrict__ pb2,
    const float* __restrict__ lnw2, const float* __restrict__ lnb2,
    const float* __restrict__ pw3, const float* __restrict__ pb3,
    const float* __restrict__ lnw3, const float* __restrict__ lnb3,
    float* __restrict__ wvb) {
    int blk = blockIdx.x;
    int l = blk >> 8;
    int rest = blk & 255;
    int b = rest >> 4, o = rest & 15;
    int c = threadIdx.x;

    const float *pw, *pb, *lnw, *lnb;
    float* outp;
    int ch;
    switch (l) {
        case 0:  pw = pw0; pb = pb0; lnw = lnw0; lnb = lnb0; outp = wvb;                 ch = 62; break;
        case 1:  pw = pw1; pb = pb1; lnw = lnw1; lnb = lnb1; outp = wvb + 15872;         ch = 16; break;
        case 2:  pw = pw2; pb = pb2; lnw = lnw2; lnb = lnb2; outp = wvb + 15872 + 4096;  ch = 16; break;
        default: pw = pw3; pb = pb3; lnw = lnw3; lnb = lnb3; outp = wvb + 15872 + 8192;  ch = 16; break;
    }
    const float* lat = latent + ((size_t)(b * 64 + l * 16 + o)) * 64;
    float dot = 0.f;
    if (c < ch) {
        const float* pr = pw + ((size_t)(o * ch + c)) * 64;
        #pragma unroll
        for (int d0 = 0; d0 < 64; d0++) dot += lat[d0] * pr[d0];
    }
    float act = (c < ch) ? dot : 0.f;
    float mu = wave_sum(act) * (1.0f / ch);
    float diff = (c < ch) ? (dot - mu) : 0.f;
    float var = wave_sum(diff * diff) * (1.0f / ch);
    float norm = diff * rsqrtf(var + 1e-5f);
    if (c < ch) outp[(size_t)(b * 16 + o) * ch + c] = norm * lnw[c] + lnb[c] + pb[o * ch + c];
}

// ---------------- kernel 3: main per-point MLP ----------------
// Structure: layers 0-3 per-thread (small, s_load weights); then w2/w3 as
// 2 passes of 52 outputs with h2_j RECOMPUTED per j (streamed, never stored).
// Max live set ~= 52 acc + 16 hb + load window => no 100-wide array anywhere.
// All shared-MLP weights staged in LDS, read as same-address broadcast
// (conflict-free), removing the SGPR-chunked s_load latency chain.
template <bool USE_H0>
__global__ __launch_bounds__(256, 2) void main_kernel(
    const float* __restrict__ x, const float* __restrict__ H0T,
    const float* __restrict__ wvb,
    const float* __restrict__ mb0, const float* __restrict__ mb1,
    const float* __restrict__ mb2, const float* __restrict__ mb3,
    const float* __restrict__ w1, const float* __restrict__ b1,
    const float* __restrict__ w2, const float* __restrict__ b2,
    const float* __restrict__ w3, const float* __restrict__ b3,
    float* __restrict__ out) {
    // ---- LDS staging of shared weights ----
    __shared__ float lds_w2t[100 * 104];  // [j][half*52 + oo], o = half*50+oo, pad oo>=50 -> 0
    __shared__ float lds_w1[100 * 16];    // row-major, same as global
    __shared__ float lds_b1[100];
    __shared__ float lds_b2[104];         // halves of 52, padded 0
    __shared__ float lds_w3[104];

    for (int idx = threadIdx.x; idx < 100 * 104; idx += 256) {
        int j = idx / 104, c = idx - j * 104;
        int half = c / 52, oo = c - half * 52;
        lds_w2t[idx] = (oo < 50) ? w2[(half * 50 + oo) * 100 + j] : 0.f;
    }
    for (int idx = threadIdx.x; idx < 1600; idx += 256) lds_w1[idx] = w1[idx];
    if (threadIdx.x < 100) lds_b1[threadIdx.x] = b1[threadIdx.x];
    if (threadIdx.x < 104) {
        int c = threadIdx.x;
        int half = c / 52, oo = c - half * 52;
        lds_b2[c] = (oo < 50) ? b2[half * 50 + oo] : 0.f;
        lds_w3[c] = (oo < 50) ? w3[half * 50 + oo] : 0.f;
    }
    __syncthreads();

    int b = blockIdx.x >> 7;
    int p = ((blockIdx.x & 127) << 8) | threadIdx.x;

#define DH(i) float h_##i;
    REP62(DH)
#undef DH
    if (USE_H0) {
#define LH(i) h_##i = H0T[(size_t)(i) * N_PTS + p];
        REP62(LH)
#undef LH
    } else {
        float x0 = x[2 * p], x1 = x[2 * p + 1];
        POSENC_BODY
    }

    const float* wv0 = wvb + b * 992;                 // [16][62]
    const float* wv1 = wvb + 15872 + b * 256;         // [16][16]
    const float* wv2 = wvb + 15872 + 4096 + b * 256;
    const float* wv3 = wvb + 15872 + 8192 + b * 256;

#define DHA(i) float ha_##i;
    REP16(DHA)
#undef DHA
#define DHB(i) float hb_##i;
    REP16(DHB)
#undef DHB

    // layer 0: h (62) -> ha (16)
#define L0T(i) acc += h_##i * wptr[i];
#define L0(o) { const float* wptr = wv0 + (o) * 62; float acc = mb0[o]; REP62(L0T) ha_##o = silu_f(acc); }
    REP16(L0)
#undef L0
    // layer 1: ha -> hb
#define LAT(i) acc += ha_##i * wptr[i];
#define LBT(i) acc += hb_##i * wptr[i];
#define L1(o) { const float* wptr = wv1 + (o) * 16; float acc = mb1[o]; REP16I(LAT) hb_##o = silu_f(acc); }
    REP16(L1)
#undef L1
    // layer 2: hb -> ha
#define L2(o) { const float* wptr = wv2 + (o) * 16; float acc = mb2[o]; REP16I(LBT) ha_##o = silu_f(acc); }
    REP16(L2)
#undef L2
    // layer 3: ha -> hb
#define L3(o) { const float* wptr = wv3 + (o) * 16; float acc = mb3[o]; REP16I(LAT) hb_##o = silu_f(acc); }
    REP16(L3)
#undef L3

    // ---- w1 -> silu -> w2 -> silu -> w3, streamed: 2 passes of 52 outputs ----
    float outv = b3[0];
    #pragma unroll 1
    for (int hf = 0; hf < 2; ++hf) {
        const int base = hf * 52;
#define AINIT(k) float acc_##k = lds_b2[base + (k)];
        REP52(AINIT)
#undef AINIT
        #pragma unroll 1
        for (int j = 0; j < 100; ++j) {
            // recompute h2_j = silu(b1[j] + hb . w1[j])
            const float4* w1r = (const float4*)(lds_w1 + j * 16);
            float4 wa = w1r[0], wb = w1r[1], wc = w1r[2], wd = w1r[3];
            float t = lds_b1[j];
            t = fmaf(hb_0,  wa.x, t); t = fmaf(hb_1,  wa.y, t);
            t = fmaf(hb_2,  wa.z, t); t = fmaf(hb_3,  wa.w, t);
            t = fmaf(hb_4,  wb.x, t); t = fmaf(hb_5,  wb.y, t);
            t = fmaf(hb_6,  wb.z, t); t = fmaf(hb_7,  wb.w, t);
            t = fmaf(hb_8,  wc.x, t); t = fmaf(hb_9,  wc.y, t);
            t = fmaf(hb_10, wc.z, t); t = fmaf(hb_11, wc.w, t);
            t = fmaf(hb_12, wd.x, t); t = fmaf(hb_13, wd.y, t);
            t = fmaf(hb_14, wd.z, t); t = fmaf(hb_15, wd.w, t);
            float h2j = silu_f(t);
            const float4* wr4 = (const float4*)(lds_w2t + j * 104 + base);
#define GRP(g, k0, k1, k2, k3) { float4 cw = wr4[g]; \
            acc_##k0 = fmaf(h2j, cw.x, acc_##k0); \
            acc_##k1 = fmaf(h2j, cw.y, acc_##k1); \
            acc_##k2 = fmaf(h2j, cw.z, acc_##k2); \
            acc_##k3 = fmaf(h2j, cw.w, acc_##k3); }
            GRP(0,0,1,2,3)     GRP(1,4,5,6,7)     GRP(2,8,9,10,11)
            GRP(3,12,13,14,15) GRP(4,16,17,18,19) GRP(5,20,21,22,23)
            GRP(6,24,25,26,27) GRP(7,28,29,30,31) GRP(8,32,33,34,35)
            GRP(9,36,37,38,39) GRP(10,40,41,42,43) GRP(11,44,45,46,47)
            GRP(12,48,49,50,51)
#undef GRP
        }
        // epilogue: out += silu(acc) * w3   (padded lanes: w3 = 0)
#define EPI(k) outv = fmaf(silu_f(acc_##k), lds_w3[base + (k)], outv);
        REP52(EPI)
#undef EPI
    }

    out[(size_t)b * N_PTS + p] = outv;
}

// ---------------- launcher ----------------
extern "C" void kernel_launch(void* const* d_in, const int* in_sizes, int n_in,
                              void* d_out, int out_size, void* d_ws, size_t ws_size,
                              hipStream_t stream) {
    const float* x = (const float*)d_in[0];
    const float* latent = (const float*)d_in[1];
    const float *pw[4], *pb[4], *lnw[4], *lnb[4], *mb[4];
    for (int l = 0; l < 4; l++) {
        pw[l]  = (const float*)d_in[2 + 5 * l];
        pb[l]  = (const float*)d_in[3 + 5 * l];
        lnw[l] = (const float*)d_in[4 + 5 * l];
        lnb[l] = (const float*)d_in[5 + 5 * l];
        mb[l]  = (const float*)d_in[6 + 5 * l];
    }
    const float* w1 = (const float*)d_in[22];
    const float* b1 = (const float*)d_in[23];
    const float* w2 = (const float*)d_in[24];
    const float* b2 = (const float*)d_in[25];
    const float* w3 = (const float*)d_in[26];
    const float* b3 = (const float*)d_in[27];

    float* wsf = (float*)d_ws;
    const size_t H0_FLOATS = (size_t)N_PTS * 62;       // feature-major H0T
    const size_t WV_FLOATS = 15872 + 3 * 4096;
    bool big = ws_size >= (H0_FLOATS + WV_FLOATS) * sizeof(float);

    float* H0T = big ? wsf : nullptr;
    float* wvb = big ? (wsf + H0_FLOATS) : wsf;

    if (big) posenc_kernel<<<128, 256, 0, stream>>>(x, H0T);
    wv_kernel<<<1024, 64, 0, stream>>>(latent,
        pw[0], pb[0], lnw[0], lnb[0],
        pw[1], pb[1], lnw[1], lnb[1],
        pw[2], pb[2], lnw[2], lnb[2],
        pw[3], pb[3], lnw[3], lnb[3],
        wvb);

    dim3 grid(BATCH * (N_PTS / 256));
    if (big) {
        main_kernel<true><<<grid, 256, 0, stream>>>(x, H0T, wvb,
            mb[0], mb[1], mb[2], mb[3], w1, b1, w2, b2, w3, b3, (float*)d_out);
    } else {
        main_kernel<false><<<grid, 256, 0, stream>>>(x, H0T, wvb,
            mb[0], mb[1], mb[2], mb[3], w1, b1, w2, b2, w3, b3, (float*)d_out);
    }
}

// Round 6
// 204.467 us; speedup vs baseline: 1.3838x; 1.3838x over previous
//
#include <hip/hip_runtime.h>

#define N_PTS 32768
#define BATCH 16
#define PIO2F 1.5707963705062866f

// ---------------- repetition macros ----------------
#define REP16(M) M(0)M(1)M(2)M(3)M(4)M(5)M(6)M(7)M(8)M(9)M(10)M(11)M(12)M(13)M(14)M(15)
#define REP16I(M) M(0)M(1)M(2)M(3)M(4)M(5)M(6)M(7)M(8)M(9)M(10)M(11)M(12)M(13)M(14)M(15)
#define REP62(M) M(0)M(1)M(2)M(3)M(4)M(5)M(6)M(7)M(8)M(9)M(10)M(11)M(12)M(13)M(14)M(15)\
M(16)M(17)M(18)M(19)M(20)M(21)M(22)M(23)M(24)M(25)M(26)M(27)M(28)M(29)M(30)M(31)\
M(32)M(33)M(34)M(35)M(36)M(37)M(38)M(39)M(40)M(41)M(42)M(43)M(44)M(45)M(46)M(47)\
M(48)M(49)M(50)M(51)M(52)M(53)M(54)M(55)M(56)M(57)M(58)M(59)M(60)M(61)

#define PE(sc, ia, ib, ic, id) { float a0 = x0 * sc, a1 = x1 * sc; \
    h_##ia = sinf(a0); h_##ib = sinf(a1); \
    h_##ic = sinf(a0 + PIO2F); h_##id = sinf(a1 + PIO2F); }
#define POSENC_BODY \
    h_0 = x0; h_1 = x1; \
    PE(1.f,2,3,32,33)      PE(2.f,4,5,34,35)      PE(4.f,6,7,36,37) \
    PE(8.f,8,9,38,39)      PE(16.f,10,11,40,41)   PE(32.f,12,13,42,43) \
    PE(64.f,14,15,44,45)   PE(128.f,16,17,46,47)  PE(256.f,18,19,48,49) \
    PE(512.f,20,21,50,51)  PE(1024.f,22,23,52,53) PE(2048.f,24,25,54,55) \
    PE(4096.f,26,27,56,57) PE(8192.f,28,29,58,59) PE(16384.f,30,31,60,61)

// ---------------- types / helpers ----------------
typedef __attribute__((ext_vector_type(8))) short short8;
typedef __attribute__((ext_vector_type(4))) float f32x4;

union S8u { short8 v; unsigned u[4]; };

__device__ __forceinline__ float silu_f(float v) {
    return v * __builtin_amdgcn_rcpf(1.0f + __expf(-v));
}

__device__ __forceinline__ float wave_sum(float v) {
    #pragma unroll
    for (int off = 1; off < 64; off <<= 1) v += __shfl_xor(v, off, 64);
    return v;
}

// split two f32 into packed bf16-hi and bf16-lo words (truncation; lo captures remainder)
__device__ __forceinline__ void bfsplit2(float a, float b, unsigned& hi, unsigned& lo) {
    unsigned ua = __float_as_uint(a), ub = __float_as_uint(b);
    hi = (ua >> 16) | (ub & 0xffff0000u);
    float ra = a - __uint_as_float(ua & 0xffff0000u);
    float rb = b - __uint_as_float(ub & 0xffff0000u);
    lo = (__float_as_uint(ra) >> 16) | (__float_as_uint(rb) & 0xffff0000u);
}

__device__ __forceinline__ f32x4 mfma16(short8 a, short8 b, f32x4 c) {
    return __builtin_amdgcn_mfma_f32_16x16x32_bf16(a, b, c, 0, 0, 0);
}

__device__ __forceinline__ short8 s8zero() {
    S8u t; t.u[0] = 0; t.u[1] = 0; t.u[2] = 0; t.u[3] = 0; return t.v;
}

// pack 8 f32 (two f32x4) into hi/lo bf16 short8 frags
__device__ __forceinline__ void packfrag(f32x4 f0, f32x4 f1, short8& h, short8& l) {
    S8u th, tl;
    bfsplit2(f0[0], f0[1], th.u[0], tl.u[0]);
    bfsplit2(f0[2], f0[3], th.u[1], tl.u[1]);
    bfsplit2(f1[0], f1[1], th.u[2], tl.u[2]);
    bfsplit2(f1[2], f1[3], th.u[3], tl.u[3]);
    h = th.v; l = tl.v;
}

// ---------------- LDS layout (bytes) ----------------
#define HB_OFF     0            // f32 [512][20]          40960
#define BOUNCE_OFF 40960        // f32 8 x [16][108]      55296
#define W2H_OFF    96256        // short [112][104]       23296
#define W2L_OFF    119552       // short [112][104]       23296
#define W1H_OFF    142848       // short [112][24]         5376
#define W1L_OFF    148224       // short [112][24]         5376
#define B1_OFF     153600       // f32 [112]                448
#define B2_OFF     154048
#define W3_OFF     154496
#define LDS_TOTAL  154944

// ---------------- kernel 1: posenc, feature-major H0T[i][p] ----------------
__global__ void posenc_kernel(const float* __restrict__ x, float* __restrict__ H0T) {
    int p = blockIdx.x * 256 + threadIdx.x;
    float x0 = x[2 * p], x1 = x[2 * p + 1];
#define DH(i) float h_##i;
    REP62(DH)
#undef DH
    POSENC_BODY
#define SH(i) H0T[(size_t)(i) * N_PTS + p] = h_##i;
    REP62(SH)
#undef SH
}

// ---------------- kernel 2: hyper-weights wv ----------------
__global__ void wv_kernel(
    const float* __restrict__ latent,
    const float* __restrict__ pw0, const float* __restrict__ pb0,
    const float* __restrict__ lnw0, const float* __restrict__ lnb0,
    const float* __restrict__ pw1, const float* __restrict__ pb1,
    const float* __restrict__ lnw1, const float* __restrict__ lnb1,
    const float* __restrict__ pw2, const float* __restrict__ pb2,
    const float* __restrict__ lnw2, const float* __restrict__ lnb2,
    const float* __restrict__ pw3, const float* __restrict__ pb3,
    const float* __restrict__ lnw3, const float* __restrict__ lnb3,
    float* __restrict__ wvb) {
    int blk = blockIdx.x;
    int l = blk >> 8;
    int rest = blk & 255;
    int b = rest >> 4, o = rest & 15;
    int c = threadIdx.x;

    const float *pw, *pb, *lnw, *lnb;
    float* outp;
    int ch;
    switch (l) {
        case 0:  pw = pw0; pb = pb0; lnw = lnw0; lnb = lnb0; outp = wvb;                 ch = 62; break;
        case 1:  pw = pw1; pb = pb1; lnw = lnw1; lnb = lnb1; outp = wvb + 15872;         ch = 16; break;
        case 2:  pw = pw2; pb = pb2; lnw = lnw2; lnb = lnb2; outp = wvb + 15872 + 4096;  ch = 16; break;
        default: pw = pw3; pb = pb3; lnw = lnw3; lnb = lnb3; outp = wvb + 15872 + 8192;  ch = 16; break;
    }
    const float* lat = latent + ((size_t)(b * 64 + l * 16 + o)) * 64;
    float dot = 0.f;
    if (c < ch) {
        const float* pr = pw + ((size_t)(o * ch + c)) * 64;
        #pragma unroll
        for (int d0 = 0; d0 < 64; d0++) dot += lat[d0] * pr[d0];
    }
    float act = (c < ch) ? dot : 0.f;
    float mu = wave_sum(act) * (1.0f / ch);
    float diff = (c < ch) ? (dot - mu) : 0.f;
    float var = wave_sum(diff * diff) * (1.0f / ch);
    float norm = diff * rsqrtf(var + 1e-5f);
    if (c < ch) outp[(size_t)(b * 16 + o) * ch + c] = norm * lnw[c] + lnb[c] + pb[o * ch + c];
}

// ---------------- kernel 3: hyper layers on VALU + shared MLP on MFMA ----------------
// Block = 512 threads (8 waves), M = 512 points, grid = 16 b * 64.
// GEMM orientation: C[feat][point]; A = weights (LDS, bf16 hi/lo), B = activations.
// 3-term bf16 split (hh + hl + lh) gives ~fp32 precision.
template <bool USE_H0>
__global__ __launch_bounds__(512, 2) void main_kernel(
    const float* __restrict__ x, const float* __restrict__ H0T,
    const float* __restrict__ wvb,
    const float* __restrict__ mb0, const float* __restrict__ mb1,
    const float* __restrict__ mb2, const float* __restrict__ mb3,
    const float* __restrict__ w1, const float* __restrict__ b1,
    const float* __restrict__ w2, const float* __restrict__ b2,
    const float* __restrict__ w3, const float* __restrict__ b3,
    float* __restrict__ out) {
    extern __shared__ char smem[];
    float* lds_hb     = (float*)(smem + HB_OFF);
    float* lds_bounce = (float*)(smem + BOUNCE_OFF);
    short* lds_w2h    = (short*)(smem + W2H_OFF);
    short* lds_w2l    = (short*)(smem + W2L_OFF);
    short* lds_w1h    = (short*)(smem + W1H_OFF);
    short* lds_w1l    = (short*)(smem + W1L_OFF);
    float* lds_b1     = (float*)(smem + B1_OFF);
    float* lds_b2     = (float*)(smem + B2_OFF);
    float* lds_w3     = (float*)(smem + W3_OFF);

    const int b  = blockIdx.x >> 6;
    const int p0 = (blockIdx.x & 63) * 512;

    // ---- stage split weights into LDS ----
    for (int idx = threadIdx.x; idx < 112 * 104; idx += 512) {
        int o = idx / 104, k = idx - o * 104;
        float v = (o < 100 && k < 100) ? w2[o * 100 + k] : 0.f;
        unsigned ua = __float_as_uint(v);
        float rv = v - __uint_as_float(ua & 0xffff0000u);
        lds_w2h[idx] = (short)(ua >> 16);
        lds_w2l[idx] = (short)(__float_as_uint(rv) >> 16);
    }
    for (int idx = threadIdx.x; idx < 112 * 24; idx += 512) {
        int o = idx / 24, k = idx - o * 24;
        float v = (o < 100 && k < 16) ? w1[o * 16 + k] : 0.f;
        unsigned ua = __float_as_uint(v);
        float rv = v - __uint_as_float(ua & 0xffff0000u);
        lds_w1h[idx] = (short)(ua >> 16);
        lds_w1l[idx] = (short)(__float_as_uint(rv) >> 16);
    }
    if (threadIdx.x < 112) {
        int o = threadIdx.x;
        lds_b1[o] = (o < 100) ? b1[o] : 0.f;
        lds_b2[o] = (o < 100) ? b2[o] : 0.f;
        lds_w3[o] = (o < 100) ? w3[o] : 0.f;
    }

    // ---- hyper phase (per thread = one point) ----
    const int p = p0 + threadIdx.x;
#define DH(i) float h_##i;
    REP62(DH)
#undef DH
    if (USE_H0) {
#define LH(i) h_##i = H0T[(size_t)(i) * N_PTS + p];
        REP62(LH)
#undef LH
    } else {
        float x0 = x[2 * p], x1 = x[2 * p + 1];
        POSENC_BODY
    }

    const float* wv0 = wvb + b * 992;
    const float* wv1 = wvb + 15872 + b * 256;
    const float* wv2 = wvb + 15872 + 4096 + b * 256;
    const float* wv3 = wvb + 15872 + 8192 + b * 256;

#define DHA(i) float ha_##i;
    REP16(DHA)
#undef DHA
#define DHB(i) float hb_##i;
    REP16(DHB)
#undef DHB

#define L0T(i) acc += h_##i * wptr[i];
#define L0(o) { const float* wptr = wv0 + (o) * 62; float acc = mb0[o]; REP62(L0T) ha_##o = silu_f(acc); }
    REP16(L0)
#undef L0
#define LAT(i) acc += ha_##i * wptr[i];
#define LBT(i) acc += hb_##i * wptr[i];
#define L1(o) { const float* wptr = wv1 + (o) * 16; float acc = mb1[o]; REP16I(LAT) hb_##o = silu_f(acc); }
    REP16(L1)
#undef L1
#define L2(o) { const float* wptr = wv2 + (o) * 16; float acc = mb2[o]; REP16I(LBT) ha_##o = silu_f(acc); }
    REP16(L2)
#undef L2
#define L3(o) { const float* wptr = wv3 + (o) * 16; float acc = mb3[o]; REP16I(LAT) hb_##o = silu_f(acc); }
    REP16(L3)
#undef L3

    // write hb row to LDS ([512][20] f32, stride 80B)
    {
        f32x4* rowp = (f32x4*)(lds_hb + threadIdx.x * 20);
        f32x4 t0 = {hb_0,  hb_1,  hb_2,  hb_3};
        f32x4 t1 = {hb_4,  hb_5,  hb_6,  hb_7};
        f32x4 t2 = {hb_8,  hb_9,  hb_10, hb_11};
        f32x4 t3 = {hb_12, hb_13, hb_14, hb_15};
        rowp[0] = t0; rowp[1] = t1; rowp[2] = t2; rowp[3] = t3;
    }
    __syncthreads();

    // ---- MFMA phase ----
    const int l    = threadIdx.x & 63;
    const int w    = threadIdx.x >> 6;
    const int lrow = l & 15;   // A feat-row / B point-col
    const int lkg  = l >> 4;   // k-group
    float* bounce = lds_bounce + w * (16 * 108);
    const int pbase = w * 64;
    const float b3v = b3[0];
    const f32x4 FZ = {0.f, 0.f, 0.f, 0.f};

    // hb B-frags for 4 point-tiles (K=16 in lower half of K=32)
    short8 hbh[4], hbl[4];
    #pragma unroll
    for (int pt = 0; pt < 4; ++pt) {
        const float* src = lds_hb + (pbase + pt * 16 + lrow) * 20 + (lkg & 1) * 8;
        f32x4 f0 = *(const f32x4*)src;
        f32x4 f1 = *(const f32x4*)(src + 4);
        if (lkg >= 2) { f0 = FZ; f1 = FZ; }
        packfrag(f0, f1, hbh[pt], hbl[pt]);
    }

    float outp_[4];
    #pragma unroll
    for (int pt = 0; pt < 4; ++pt) outp_[pt] = 0.f;

    // ---- w1 per point-tile -> bounce -> build h2 frags ----
    short8 h2h[4][4], h2l[4][4];
    #pragma unroll
    for (int pt = 0; pt < 4; ++pt) {
        #pragma unroll
        for (int fmt = 0; fmt < 7; ++fmt) {
            f32x4 acc;
            #pragma unroll
            for (int r = 0; r < 4; ++r) acc[r] = lds_b1[fmt * 16 + lkg * 4 + r];
            short8 ah = *(const short8*)(lds_w1h + (fmt * 16 + lrow) * 24 + (lkg & 1) * 8);
            short8 al = *(const short8*)(lds_w1l + (fmt * 16 + lrow) * 24 + (lkg & 1) * 8);
            if (lkg >= 2) { ah = s8zero(); al = s8zero(); }
            acc = mfma16(ah, hbh[pt], acc);
            acc = mfma16(ah, hbl[pt], acc);
            acc = mfma16(al, hbh[pt], acc);
            // silu -> bounce[point][feat], 4 consecutive feats per lane
            f32x4 sv;
            #pragma unroll
            for (int r = 0; r < 4; ++r) sv[r] = silu_f(acc[r]);
            if (!(fmt == 6 && lkg == 3))
                *(f32x4*)(bounce + lrow * 108 + fmt * 16 + lkg * 4) = sv;
        }
        // build h2 frags for this point-tile (K=128, k>=104 zeroed; cols 100-103 are 0)
        #pragma unroll
        for (int ks = 0; ks < 4; ++ks) {
            int kb = ks * 32 + lkg * 8;
            bool act = kb < 104;
            int kba = act ? kb : 0;
            const float* s2 = bounce + lrow * 108 + kba;
            f32x4 f0 = *(const f32x4*)s2;
            f32x4 f1 = *(const f32x4*)(s2 + 4);
            if (!act) { f0 = FZ; f1 = FZ; }
            packfrag(f0, f1, h2h[pt][ks], h2l[pt][ks]);
        }
    }

    // ---- w2: weights stream from LDS, h2 resident in registers ----
    #pragma unroll
    for (int fmt = 0; fmt < 7; ++fmt) {
        float bi[4], w3r[4];
        #pragma unroll
        for (int r = 0; r < 4; ++r) {
            bi[r]  = lds_b2[fmt * 16 + lkg * 4 + r];
            w3r[r] = lds_w3[fmt * 16 + lkg * 4 + r];
        }
        f32x4 acc[4];
        #pragma unroll
        for (int pt = 0; pt < 4; ++pt) { f32x4 t = {bi[0], bi[1], bi[2], bi[3]}; acc[pt] = t; }
        #pragma unroll
        for (int ks = 0; ks < 4; ++ks) {
            int kb = ks * 32 + lkg * 8;
            bool act = kb < 104;
            int kba = act ? kb : 0;
            short8 ah = *(const short8*)(lds_w2h + (fmt * 16 + lrow) * 104 + kba);
            short8 al = *(const short8*)(lds_w2l + (fmt * 16 + lrow) * 104 + kba);
            if (!act) { ah = s8zero(); al = s8zero(); }
            #pragma unroll
            for (int pt = 0; pt < 4; ++pt) {
                acc[pt] = mfma16(ah, h2h[pt][ks], acc[pt]);
                acc[pt] = mfma16(ah, h2l[pt][ks], acc[pt]);
                acc[pt] = mfma16(al, h2h[pt][ks], acc[pt]);
            }
        }
        // epilogue: out-partial += silu(h3) * w3[feat]
        #pragma unroll
        for (int pt = 0; pt < 4; ++pt) {
            #pragma unroll
            for (int r = 0; r < 4; ++r)
                outp_[pt] = fmaf(silu_f(acc[pt][r]), w3r[r], outp_[pt]);
        }
    }

    // reduce across the 4 lane-groups and store
    float vred[4];
    #pragma unroll
    for (int pt = 0; pt < 4; ++pt) {
        float v = outp_[pt];
        v += __shfl_xor(v, 16, 64);
        v += __shfl_xor(v, 32, 64);
        vred[pt] = v;
    }
    if (l < 16) {
        #pragma unroll
        for (int pt = 0; pt < 4; ++pt)
            out[(size_t)b * N_PTS + p0 + pbase + pt * 16 + lrow] = vred[pt] + b3v;
    }
}

// ---------------- launcher ----------------
extern "C" void kernel_launch(void* const* d_in, const int* in_sizes, int n_in,
                              void* d_out, int out_size, void* d_ws, size_t ws_size,
                              hipStream_t stream) {
    const float* x = (const float*)d_in[0];
    const float* latent = (const float*)d_in[1];
    const float *pw[4], *pb[4], *lnw[4], *lnb[4], *mb[4];
    for (int l = 0; l < 4; l++) {
        pw[l]  = (const float*)d_in[2 + 5 * l];
        pb[l]  = (const float*)d_in[3 + 5 * l];
        lnw[l] = (const float*)d_in[4 + 5 * l];
        lnb[l] = (const float*)d_in[5 + 5 * l];
        mb[l]  = (const float*)d_in[6 + 5 * l];
    }
    const float* w1 = (const float*)d_in[22];
    const float* b1 = (const float*)d_in[23];
    const float* w2 = (const float*)d_in[24];
    const float* b2 = (const float*)d_in[25];
    const float* w3 = (const float*)d_in[26];
    const float* b3 = (const float*)d_in[27];

    float* wsf = (float*)d_ws;
    const size_t H0_FLOATS = (size_t)N_PTS * 62;
    const size_t WV_FLOATS = 15872 + 3 * 4096;
    bool big = ws_size >= (H0_FLOATS + WV_FLOATS) * sizeof(float);

    float* H0T = big ? wsf : nullptr;
    float* wvb = big ? (wsf + H0_FLOATS) : wsf;

    if (big) posenc_kernel<<<128, 256, 0, stream>>>(x, H0T);
    wv_kernel<<<1024, 64, 0, stream>>>(latent,
        pw[0], pb[0], lnw[0], lnb[0],
        pw[1], pb[1], lnw[1], lnb[1],
        pw[2], pb[2], lnw[2], lnb[2],
        pw[3], pb[3], lnw[3], lnb[3],
        wvb);

    dim3 grid(BATCH * (N_PTS / 512));
    if (big) {
        hipFuncSetAttribute((const void*)main_kernel<true>,
                            hipFuncAttributeMaxDynamicSharedMemorySize, LDS_TOTAL);
        main_kernel<true><<<grid, 512, LDS_TOTAL, stream>>>(x, H0T, wvb,
            mb[0], mb[1], mb[2], mb[3], w1, b1, w2, b2, w3, b3, (float*)d_out);
    } else {
        hipFuncSetAttribute((const void*)main_kernel<false>,
                            hipFuncAttributeMaxDynamicSharedMemorySize, LDS_TOTAL);
        main_kernel<false><<<grid, 512, LDS_TOTAL, stream>>>(x, H0T, wvb,
            mb[0], mb[1], mb[2], mb[3], w1, b1, w2, b2, w3, b3, (float*)d_out);
    }
}